// Round 17
// baseline (242.519 us; speedup 1.0000x reference)
//
#include <hip/hip_runtime.h>

#define KK 27
#define INC 32
#define PC 64

typedef __attribute__((ext_vector_type(8))) short v8s;
typedef __attribute__((ext_vector_type(4))) float f32x4;

static __device__ __forceinline__ float b2f(ushort u) {
  union { float f; unsigned int i; } x; x.i = ((unsigned int)u) << 16; return x.f;
}
static __device__ __forceinline__ ushort f2b(float f) {
  union { float f; unsigned int i; } x; x.f = f;
  unsigned int u = x.i;
  unsigned int r = (u + 0x7FFFu + ((u >> 16) & 1u)) >> 16;
  return (ushort)r;
}

// ---------------- Kernel 1 (R16): MFMA-based prep. 64 voxels/block, 4 waves.
__global__ __launch_bounds__(256) void k_prep2(
    const float* __restrict__ xf, const ushort* __restrict__ Wtp, const float* __restrict__ bt,
    const ushort* __restrict__ Wvp, const float* __restrict__ bv,
    const ushort* __restrict__ Wqp, const int* __restrict__ coords,
    ushort* __restrict__ v, ushort* __restrict__ zc16, int N)
{
  const int tid = threadIdx.x;
  const int lane = tid & 63, w = tid >> 6;
  const int ln = lane & 15, grp = lane >> 4;
  const int base = blockIdx.x * 64;

  __shared__ __align__(16) ushort xfb[64][40];   // xf bf16, K=32 (pad 40)
  __shared__ __align__(16) ushort xb[64][72];    // x bf16, K=64 (pad 72)

  {
    int r = tid >> 2, c0 = (tid & 3) * 8;
    int n = base + r;
    v8s d = {0,0,0,0,0,0,0,0};
    if (n < N) {
      float4 f0 = *(const float4*)(xf + (size_t)n * INC + c0);
      float4 f1 = *(const float4*)(xf + (size_t)n * INC + c0 + 4);
      d[0] = (short)f2b(f0.x); d[1] = (short)f2b(f0.y);
      d[2] = (short)f2b(f0.z); d[3] = (short)f2b(f0.w);
      d[4] = (short)f2b(f1.x); d[5] = (short)f2b(f1.y);
      d[6] = (short)f2b(f1.z); d[7] = (short)f2b(f1.w);
    }
    *(v8s*)(&xfb[r][c0]) = d;
  }
  if (tid < 64) {
    int n = base + tid;
    if (n < N) {
      ushort* row = zc16 + (size_t)n * 32;
      row[0] = (ushort)coords[n * 3 + 0];
      row[1] = (ushort)coords[n * 3 + 1];
      row[2] = (ushort)coords[n * 3 + 2];
      row[3] = 0;
    }
  }
  __syncthreads();

  const int d = w * 16 + ln;
  // phase 1: x = relu(xf@Wt+bt)
  {
    v8s wtf = *(const v8s*)(Wtp + (size_t)d * 32 + grp * 8);
    float btv = bt[d];
    #pragma unroll
    for (int mt = 0; mt < 4; ++mt) {
      v8s af = *(const v8s*)(&xfb[mt * 16 + ln][grp * 8]);
      f32x4 z4 = {0.f, 0.f, 0.f, 0.f};
      f32x4 acc = __builtin_amdgcn_mfma_f32_16x16x32_bf16(af, wtf, z4, 0, 0, 0);
      #pragma unroll
      for (int i = 0; i < 4; ++i) {
        int row = mt * 16 + grp * 4 + i;
        xb[row][d] = f2b(fmaxf(acc[i] + btv, 0.f));
      }
    }
  }
  __syncthreads();

  // phase 2: v = relu(x@Wv+bv)
  {
    v8s wv0 = *(const v8s*)(Wvp + (size_t)d * 64 + grp * 8);
    v8s wv1 = *(const v8s*)(Wvp + (size_t)d * 64 + 32 + grp * 8);
    float bvv = bv[d];
    #pragma unroll
    for (int mt = 0; mt < 4; ++mt) {
      v8s a0 = *(const v8s*)(&xb[mt * 16 + ln][grp * 8]);
      v8s a1 = *(const v8s*)(&xb[mt * 16 + ln][32 + grp * 8]);
      f32x4 acc = {0.f, 0.f, 0.f, 0.f};
      acc = __builtin_amdgcn_mfma_f32_16x16x32_bf16(a0, wv0, acc, 0, 0, 0);
      acc = __builtin_amdgcn_mfma_f32_16x16x32_bf16(a1, wv1, acc, 0, 0, 0);
      #pragma unroll
      for (int i = 0; i < 4; ++i) {
        int row = mt * 16 + grp * 4 + i;
        int n = base + row;
        if (n < N) v[(size_t)n * PC + d] = f2b(fmaxf(acc[i] + bvv, 0.f));
      }
    }
  }

  // phase 3: z = x@Wq^T
  {
    const int kcol = (w & 1) * 16 + ln;
    v8s wq0 = *(const v8s*)(Wqp + (size_t)kcol * 64 + grp * 8);
    v8s wq1 = *(const v8s*)(Wqp + (size_t)kcol * 64 + 32 + grp * 8);
    #pragma unroll
    for (int mtt = 0; mtt < 2; ++mtt) {
      int mt = 2 * (w >> 1) + mtt;
      v8s a0 = *(const v8s*)(&xb[mt * 16 + ln][grp * 8]);
      v8s a1 = *(const v8s*)(&xb[mt * 16 + ln][32 + grp * 8]);
      f32x4 acc = {0.f, 0.f, 0.f, 0.f};
      acc = __builtin_amdgcn_mfma_f32_16x16x32_bf16(a0, wq0, acc, 0, 0, 0);
      acc = __builtin_amdgcn_mfma_f32_16x16x32_bf16(a1, wq1, acc, 0, 0, 0);
      if (kcol < KK) {
        #pragma unroll
        for (int i = 0; i < 4; ++i) {
          int row = mt * 16 + grp * 4 + i;
          int n = base + row;
          if (n < N) zc16[(size_t)n * 32 + 4 + kcol] = f2b(acc[i]);
        }
      }
    }
  }
}

// ---------------- Kernel 2: repack W_code->Bp, Wd->Wdp, Wt->Wtp, Wv->Wvp, Wq->Wqp
__global__ __launch_bounds__(256) void k_prepBD(
    const float* __restrict__ Wcode, const float* __restrict__ Wd,
    const float* __restrict__ Wt, const float* __restrict__ Wv, const float* __restrict__ Wq,
    ushort* __restrict__ Bp, ushort* __restrict__ Wdp,
    ushort* __restrict__ Wtp, ushort* __restrict__ Wvp, ushort* __restrict__ Wqp)
{
  int bid = blockIdx.x;
  if (bid < 1728) {
    int i = bid * 256 + threadIdx.x;   // 442368
    int j = i & 7;
    int col = (i >> 3) & 255;
    int kg = (i >> 11) & 3;
    int s = i >> 13;
    int k = s * 32 + kg * 8 + j;
    int m = col >> 6, dd = col & 63;
    int knbr = k >> 6, c = k & 63;
    Bp[i] = f2b(Wcode[(((m * KK + knbr) * 64) + c) * 64 + dd]);
  } else if (bid < 1736) {
    int i = (bid - 1728) * 256 + threadIdx.x;
    int col = i >> 5, k = i & 31;
    Wdp[i] = f2b(Wd[k * PC + col]);
  } else if (bid < 1744) {
    int i = (bid - 1736) * 256 + threadIdx.x;
    int col = i >> 5, k = i & 31;
    Wtp[i] = f2b(Wt[k * PC + col]);
  } else if (bid < 1760) {
    int i = (bid - 1744) * 256 + threadIdx.x;
    int col = i >> 6, k = i & 63;
    Wvp[i] = f2b(Wv[k * PC + col]);
  } else {
    int i = (bid - 1760) * 256 + threadIdx.x;
    int kcol = i >> 6, c = i & 63;
    Wqp[i] = (kcol < KK) ? f2b(Wq[kcol * PC + c]) : (ushort)0;
  }
}

// ---------------- Kernel 3: PARALLEL-k attention (R14, unchanged)
__global__ __launch_bounds__(256) void k_attn2(
    const int* __restrict__ nbr_idx, const int* __restrict__ nbr_mask,
    const ushort* __restrict__ zc16,
    const float* __restrict__ Wpos, const float* __restrict__ bpos,
    const float* __restrict__ Wq, const float* __restrict__ bq,
    const float* __restrict__ proj, float* __restrict__ attn, int N)
{
  int tid = threadIdx.x;
  int wv = tid >> 6, lane = tid & 63;
  int half = lane >> 5, l = lane & 31;
  int n = blockIdx.x * 8 + wv * 2 + half;
  bool vok = (n < N);
  int j = -1;
  if (vok && l < KK) {
    if (nbr_mask[(size_t)n * KK + l]) j = nbr_idx[(size_t)n * KK + l];
  }
  int cx = 0, cy = 0, cz = 0;
  if (vok) {
    uint2 cd = *(const uint2*)(zc16 + (size_t)n * 32);
    cx = (int)(cd.x & 0xffffu); cy = (int)(cd.x >> 16); cz = (int)(cd.y & 0xffffu);
  }
  float qc = 0.f;
  if (j >= 0) {
    uint2 cj = *(const uint2*)(zc16 + (size_t)j * 32);
    float z = b2f(zc16[(size_t)j * 32 + 4 + l]);
    float rx = (float)((int)(cj.x & 0xffffu) - cx);
    float ry = (float)((int)(cj.x >> 16) - cy);
    float rz = (float)((int)(cj.y & 0xffffu) - cz);
    float t = 0.f;
    #pragma unroll
    for (int c4 = 0; c4 < 16; ++c4) {
      float4 w0 = *(const float4*)(Wpos + c4 * 4);
      float4 w1 = *(const float4*)(Wpos + 64 + c4 * 4);
      float4 w2 = *(const float4*)(Wpos + 128 + c4 * 4);
      float4 bp = *(const float4*)(bpos + c4 * 4);
      float4 wq = *(const float4*)(Wq + (size_t)l * PC + c4 * 4);
      t += fmaxf(rx * w0.x + ry * w1.x + rz * w2.x + bp.x, 0.f) * wq.x;
      t += fmaxf(rx * w0.y + ry * w1.y + rz * w2.y + bp.y, 0.f) * wq.y;
      t += fmaxf(rx * w0.z + ry * w1.z + rz * w2.z + bp.z, 0.f) * wq.z;
      t += fmaxf(rx * w0.w + ry * w1.w + rz * w2.w + bp.w, 0.f) * wq.w;
    }
    qc = z + t;
  }
  qc += __shfl_xor(qc, 1); qc += __shfl_xor(qc, 2); qc += __shfl_xor(qc, 4);
  qc += __shfl_xor(qc, 8); qc += __shfl_xor(qc, 16);
  if (vok && l == 0) {
    float q = fmaxf(qc + bq[0], 0.f);
    float lg[4], mx = -1e30f;
    #pragma unroll
    for (int m = 0; m < 4; ++m) { lg[m] = q * proj[m] * 0.1f; mx = fmaxf(mx, lg[m]); }
    float s = 0.f;
    #pragma unroll
    for (int m = 0; m < 4; ++m) { lg[m] = __expf(lg[m] - mx); s += lg[m]; }
    float inv = 1.f / s;
    #pragma unroll
    for (int m = 0; m < 4; ++m) attn[(size_t)n * 4 + m] = lg[m] * inv;
  }
}

// ---------------- Kernel 4 (R17): gathered GEMM, BM=128, 8 waves.
// Waves 0-3 rows 0-63, waves 4-7 rows 64-127; col-slice ws=w&3 as in R9.
// Per-wave shape IDENTICAL to R9 (acc[4][4], 32 MFMA/kn, 2 uint4 staged/thread).
// B re-read by second row-half is L1/L2-hot -> B L2 traffic per row halves.
__global__ __launch_bounds__(512) void k_code(
    const ushort* __restrict__ v, const int* __restrict__ nbr_idx, const int* __restrict__ nbr_mask,
    const ushort* __restrict__ Bp, const float* __restrict__ attn,
    const float* __restrict__ xf, const ushort* __restrict__ Wdp, const float* __restrict__ bd,
    const float* __restrict__ bcode, float* __restrict__ out, int N)
{
  const int tid = threadIdx.x;
  const int lane = tid & 63, w = tid >> 6;
  const int ws = w & 3, rh = w >> 2;
  const int base = blockIdx.x * 128;

  __shared__ __align__(16) union SM {
    struct { ushort As[3][8192]; int jm[128][KK]; } g;   // 48K + 13.5K = 61.5 KB
    struct { ushort xfb[128][40]; } e;                   // 10.2 KB
  } sm;

  for (int i = tid; i < 128 * KK; i += 512) {
    int r = i / KK, k = i % KK;
    int n = base + r;
    int val = -1;
    if (n < N && nbr_mask[(size_t)n * KK + k]) val = nbr_idx[(size_t)n * KK + k];
    sm.g.jm[r][k] = val;
  }

  const int r0 = tid >> 3, cc0 = tid & 7;
  const int r1 = r0 + 64;
  const int sc0 = cc0 ^ (r0 & 7), sc1 = cc0 ^ (r1 & 7);

  __syncthreads();  // jm ready

  // prologue: gather(0) -> As[0]; gather(1) -> regs R
  uint4 R0 = make_uint4(0u,0u,0u,0u), R1 = R0;
  {
    int j0 = sm.g.jm[r0][0], j1 = sm.g.jm[r1][0];
    uint4 p0 = make_uint4(0u, 0u, 0u, 0u), p1 = p0;
    if (j0 >= 0) p0 = *(const uint4*)(v + (size_t)j0 * PC + cc0 * 8);
    if (j1 >= 0) p1 = *(const uint4*)(v + (size_t)j1 * PC + cc0 * 8);
    int jc = sm.g.jm[r0][1], jd = sm.g.jm[r1][1];
    if (jc >= 0) R0 = *(const uint4*)(v + (size_t)jc * PC + cc0 * 8);
    if (jd >= 0) R1 = *(const uint4*)(v + (size_t)jd * PC + cc0 * 8);
    *(uint4*)(&sm.g.As[0][r0 * 64 + sc0 * 8]) = p0;
    *(uint4*)(&sm.g.As[0][r1 * 64 + sc1 * 8]) = p1;
  }
  __syncthreads();

  f32x4 acc[4][4] = {};
  // col = nt*64 + ws*16 + (lane&15)  -> nt stride = 512 ushorts
  const ushort* bbase = Bp + (size_t)(lane >> 4) * 2048 + (size_t)((ws << 4) + (lane & 15)) * 8;

  int cur = 0, nx = 1;
  for (int kn = 0; kn < KK; ++kn) {
    // (1) B fragments — issued FIRST (MFMA's vmcnt stops here)
    v8s bf0[4], bf1[4];
    {
      const ushort* bb0 = bbase + (size_t)(8 * kn) * 2048;
      const ushort* bb1 = bb0 + 4 * 2048;
      #pragma unroll
      for (int nt = 0; nt < 4; ++nt) {
        bf0[nt] = *(const v8s*)(bb0 + nt * 512);
        bf1[nt] = *(const v8s*)(bb1 + nt * 512);
      }
    }
    // (2) EARLY COMMIT: gather(kn+1) -> As[nx]
    if (kn + 1 < KK) {
      *(uint4*)(&sm.g.As[nx][r0 * 64 + sc0 * 8]) = R0;
      *(uint4*)(&sm.g.As[nx][r1 * 64 + sc1 * 8]) = R1;
    }
    // (3) issue gather(kn+2) -> R
    R0 = make_uint4(0u,0u,0u,0u); R1 = R0;
    if (kn + 2 < KK) {
      int j0 = sm.g.jm[r0][kn + 2], j1 = sm.g.jm[r1][kn + 2];
      if (j0 >= 0) R0 = *(const uint4*)(v + (size_t)j0 * PC + cc0 * 8);
      if (j1 >= 0) R1 = *(const uint4*)(v + (size_t)j1 * PC + cc0 * 8);
    }
    // (4) A fragments + MFMA on As[cur]: rows rh*64 + mt*16
    #pragma unroll
    for (int s2 = 0; s2 < 2; ++s2) {
      v8s af[4];
      const int cc = s2 * 4 + (lane >> 4);
      #pragma unroll
      for (int mt = 0; mt < 4; ++mt) {
        const int r = rh * 64 + mt * 16 + (lane & 15);
        const int sc = cc ^ (r & 7);
        af[mt] = *(const v8s*)(&sm.g.As[cur][r * 64 + sc * 8]);
      }
      #pragma unroll
      for (int mt = 0; mt < 4; ++mt)
        #pragma unroll
        for (int nt = 0; nt < 4; ++nt)
          acc[mt][nt] = __builtin_amdgcn_mfma_f32_16x16x32_bf16(
              af[mt], (s2 ? bf1[nt] : bf0[nt]), acc[mt][nt], 0, 0, 0);
    }
    __syncthreads();
    cur = nx; nx = (nx == 2) ? 0 : nx + 1;
  }

  // ---- epilogue: per-lane m-sum + MFMA residual
  for (int i2 = tid; i2 < 4096; i2 += 512) {
    int r = i2 >> 5, c = i2 & 31;
    int n = base + r;
    sm.e.xfb[r][c] = (n < N) ? f2b(xf[(size_t)n * INC + c]) : (ushort)0;
  }
  __syncthreads();

  const int ln = lane & 15, grp = lane >> 4;
  const int d = (ws << 4) + ln;
  v8s wdf = *(const v8s*)(Wdp + (size_t)d * 32 + grp * 8);
  f32x4 res[4];
  #pragma unroll
  for (int mt = 0; mt < 4; ++mt) {
    v8s af = *(const v8s*)(&sm.e.xfb[rh * 64 + mt * 16 + ln][grp * 8]);
    f32x4 z = {0.f, 0.f, 0.f, 0.f};
    res[mt] = __builtin_amdgcn_mfma_f32_16x16x32_bf16(af, wdf, z, 0, 0, 0);
  }
  float bcv[4];
  #pragma unroll
  for (int nt = 0; nt < 4; ++nt) bcv[nt] = bcode[nt * PC + d];
  const float bdv = bd[d];
  #pragma unroll
  for (int mt = 0; mt < 4; ++mt) {
    #pragma unroll
    for (int i = 0; i < 4; ++i) {
      int row = rh * 64 + mt * 16 + grp * 4 + i;
      int n = base + row;
      if (n < N) {
        float4 a4 = *(const float4*)(attn + (size_t)n * 4);
        float val = res[mt][i] + bdv;
        val += a4.x * fmaxf(acc[mt][0][i] + bcv[0], 0.f);
        val += a4.y * fmaxf(acc[mt][1][i] + bcv[1], 0.f);
        val += a4.z * fmaxf(acc[mt][2][i] + bcv[2], 0.f);
        val += a4.w * fmaxf(acc[mt][3][i] + bcv[3], 0.f);
        out[(size_t)n * PC + d] = fmaxf(val, 0.f);
      }
    }
  }
}

extern "C" void kernel_launch(void* const* d_in, const int* in_sizes, int n_in,
                              void* d_out, int out_size, void* d_ws, size_t ws_size,
                              hipStream_t stream)
{
  const float* xf     = (const float*)d_in[0];
  const int* nbr_idx  = (const int*)d_in[1];
  const int* nbr_mask = (const int*)d_in[2];
  const int* coords   = (const int*)d_in[3];
  const float* Wt     = (const float*)d_in[4];
  const float* bt     = (const float*)d_in[5];
  const float* Wd     = (const float*)d_in[6];
  const float* bd     = (const float*)d_in[7];
  const float* Wpos   = (const float*)d_in[8];
  const float* bpos   = (const float*)d_in[9];
  const float* Wq     = (const float*)d_in[10];
  const float* bq     = (const float*)d_in[11];
  const float* proj   = (const float*)d_in[12];
  const float* Wv     = (const float*)d_in[13];
  const float* bv     = (const float*)d_in[14];
  const float* Wcode  = (const float*)d_in[15];
  const float* bcode  = (const float*)d_in[16];
  float* out = (float*)d_out;

  int N = in_sizes[0] / INC;

  char* ws = (char*)d_ws;
  size_t off = 0;
  auto alloc = [&](size_t bytes) {
    off = (off + 255) & ~(size_t)255;
    void* p = ws + off;
    off += bytes;
    return p;
  };
  ushort* v_ws  = (ushort*)alloc((size_t)N * PC * 2);
  ushort* zc_ws = (ushort*)alloc((size_t)N * 32 * 2);
  float*  a_ws  = (float*)alloc((size_t)N * 4 * 4);
  ushort* B_ws  = (ushort*)alloc((size_t)54 * 4 * 256 * 8 * 2);
  ushort* D_ws  = (ushort*)alloc((size_t)2048 * 2);
  ushort* T_ws  = (ushort*)alloc((size_t)2048 * 2);
  ushort* V2_ws = (ushort*)alloc((size_t)4096 * 2);
  ushort* Q_ws  = (ushort*)alloc((size_t)2048 * 2);
  (void)ws_size;

  hipLaunchKernelGGL(k_prepBD, dim3(1768), dim3(256), 0, stream,
                     Wcode, Wd, Wt, Wv, Wq, B_ws, D_ws, T_ws, V2_ws, Q_ws);
  hipLaunchKernelGGL(k_prep2, dim3((N + 63) / 64), dim3(256), 0, stream,
                     xf, T_ws, bt, V2_ws, bv, Q_ws, coords, v_ws, zc_ws, N);
  hipLaunchKernelGGL(k_attn2, dim3((N + 7) / 8), dim3(256), 0, stream,
                     nbr_idx, nbr_mask, zc_ws, Wpos, bpos, Wq, bq, proj, a_ws, N);
  hipLaunchKernelGGL(k_code, dim3((N + 127) / 128), dim3(512), 0, stream,
                     v_ws, nbr_idx, nbr_mask, B_ws, a_ws, xf, D_ws, bd, bcode, out, N);
}

// Round 18
// 195.334 us; speedup vs baseline: 1.2416x; 1.2416x over previous
//
#include <hip/hip_runtime.h>

#define KK 27
#define INC 32
#define PC 64

typedef __attribute__((ext_vector_type(8))) short v8s;
typedef __attribute__((ext_vector_type(4))) float f32x4;

static __device__ __forceinline__ float b2f(ushort u) {
  union { float f; unsigned int i; } x; x.i = ((unsigned int)u) << 16; return x.f;
}
static __device__ __forceinline__ ushort f2b(float f) {
  union { float f; unsigned int i; } x; x.f = f;
  unsigned int u = x.i;
  unsigned int r = (u + 0x7FFFu + ((u >> 16) & 1u)) >> 16;
  return (ushort)r;
}

// ---------------- Kernel 1 (R16): MFMA-based prep. 64 voxels/block, 4 waves.
__global__ __launch_bounds__(256) void k_prep2(
    const float* __restrict__ xf, const ushort* __restrict__ Wtp, const float* __restrict__ bt,
    const ushort* __restrict__ Wvp, const float* __restrict__ bv,
    const ushort* __restrict__ Wqp, const int* __restrict__ coords,
    ushort* __restrict__ v, ushort* __restrict__ zc16, int N)
{
  const int tid = threadIdx.x;
  const int lane = tid & 63, w = tid >> 6;
  const int ln = lane & 15, grp = lane >> 4;
  const int base = blockIdx.x * 64;

  __shared__ __align__(16) ushort xfb[64][40];
  __shared__ __align__(16) ushort xb[64][72];

  {
    int r = tid >> 2, c0 = (tid & 3) * 8;
    int n = base + r;
    v8s d = {0,0,0,0,0,0,0,0};
    if (n < N) {
      float4 f0 = *(const float4*)(xf + (size_t)n * INC + c0);
      float4 f1 = *(const float4*)(xf + (size_t)n * INC + c0 + 4);
      d[0] = (short)f2b(f0.x); d[1] = (short)f2b(f0.y);
      d[2] = (short)f2b(f0.z); d[3] = (short)f2b(f0.w);
      d[4] = (short)f2b(f1.x); d[5] = (short)f2b(f1.y);
      d[6] = (short)f2b(f1.z); d[7] = (short)f2b(f1.w);
    }
    *(v8s*)(&xfb[r][c0]) = d;
  }
  if (tid < 64) {
    int n = base + tid;
    if (n < N) {
      ushort* row = zc16 + (size_t)n * 32;
      row[0] = (ushort)coords[n * 3 + 0];
      row[1] = (ushort)coords[n * 3 + 1];
      row[2] = (ushort)coords[n * 3 + 2];
      row[3] = 0;
    }
  }
  __syncthreads();

  const int d = w * 16 + ln;
  {
    v8s wtf = *(const v8s*)(Wtp + (size_t)d * 32 + grp * 8);
    float btv = bt[d];
    #pragma unroll
    for (int mt = 0; mt < 4; ++mt) {
      v8s af = *(const v8s*)(&xfb[mt * 16 + ln][grp * 8]);
      f32x4 z4 = {0.f, 0.f, 0.f, 0.f};
      f32x4 acc = __builtin_amdgcn_mfma_f32_16x16x32_bf16(af, wtf, z4, 0, 0, 0);
      #pragma unroll
      for (int i = 0; i < 4; ++i) {
        int row = mt * 16 + grp * 4 + i;
        xb[row][d] = f2b(fmaxf(acc[i] + btv, 0.f));
      }
    }
  }
  __syncthreads();

  {
    v8s wv0 = *(const v8s*)(Wvp + (size_t)d * 64 + grp * 8);
    v8s wv1 = *(const v8s*)(Wvp + (size_t)d * 64 + 32 + grp * 8);
    float bvv = bv[d];
    #pragma unroll
    for (int mt = 0; mt < 4; ++mt) {
      v8s a0 = *(const v8s*)(&xb[mt * 16 + ln][grp * 8]);
      v8s a1 = *(const v8s*)(&xb[mt * 16 + ln][32 + grp * 8]);
      f32x4 acc = {0.f, 0.f, 0.f, 0.f};
      acc = __builtin_amdgcn_mfma_f32_16x16x32_bf16(a0, wv0, acc, 0, 0, 0);
      acc = __builtin_amdgcn_mfma_f32_16x16x32_bf16(a1, wv1, acc, 0, 0, 0);
      #pragma unroll
      for (int i = 0; i < 4; ++i) {
        int row = mt * 16 + grp * 4 + i;
        int n = base + row;
        if (n < N) v[(size_t)n * PC + d] = f2b(fmaxf(acc[i] + bvv, 0.f));
      }
    }
  }

  {
    const int kcol = (w & 1) * 16 + ln;
    v8s wq0 = *(const v8s*)(Wqp + (size_t)kcol * 64 + grp * 8);
    v8s wq1 = *(const v8s*)(Wqp + (size_t)kcol * 64 + 32 + grp * 8);
    #pragma unroll
    for (int mtt = 0; mtt < 2; ++mtt) {
      int mt = 2 * (w >> 1) + mtt;
      v8s a0 = *(const v8s*)(&xb[mt * 16 + ln][grp * 8]);
      v8s a1 = *(const v8s*)(&xb[mt * 16 + ln][32 + grp * 8]);
      f32x4 acc = {0.f, 0.f, 0.f, 0.f};
      acc = __builtin_amdgcn_mfma_f32_16x16x32_bf16(a0, wq0, acc, 0, 0, 0);
      acc = __builtin_amdgcn_mfma_f32_16x16x32_bf16(a1, wq1, acc, 0, 0, 0);
      if (kcol < KK) {
        #pragma unroll
        for (int i = 0; i < 4; ++i) {
          int row = mt * 16 + grp * 4 + i;
          int n = base + row;
          if (n < N) zc16[(size_t)n * 32 + 4 + kcol] = f2b(acc[i]);
        }
      }
    }
  }
}

// ---------------- Kernel 2: repack weights (unchanged)
__global__ __launch_bounds__(256) void k_prepBD(
    const float* __restrict__ Wcode, const float* __restrict__ Wd,
    const float* __restrict__ Wt, const float* __restrict__ Wv, const float* __restrict__ Wq,
    ushort* __restrict__ Bp, ushort* __restrict__ Wdp,
    ushort* __restrict__ Wtp, ushort* __restrict__ Wvp, ushort* __restrict__ Wqp)
{
  int bid = blockIdx.x;
  if (bid < 1728) {
    int i = bid * 256 + threadIdx.x;
    int j = i & 7;
    int col = (i >> 3) & 255;
    int kg = (i >> 11) & 3;
    int s = i >> 13;
    int k = s * 32 + kg * 8 + j;
    int m = col >> 6, dd = col & 63;
    int knbr = k >> 6, c = k & 63;
    Bp[i] = f2b(Wcode[(((m * KK + knbr) * 64) + c) * 64 + dd]);
  } else if (bid < 1736) {
    int i = (bid - 1728) * 256 + threadIdx.x;
    int col = i >> 5, k = i & 31;
    Wdp[i] = f2b(Wd[k * PC + col]);
  } else if (bid < 1744) {
    int i = (bid - 1736) * 256 + threadIdx.x;
    int col = i >> 5, k = i & 31;
    Wtp[i] = f2b(Wt[k * PC + col]);
  } else if (bid < 1760) {
    int i = (bid - 1744) * 256 + threadIdx.x;
    int col = i >> 6, k = i & 63;
    Wvp[i] = f2b(Wv[k * PC + col]);
  } else {
    int i = (bid - 1760) * 256 + threadIdx.x;
    int kcol = i >> 6, c = i & 63;
    Wqp[i] = (kcol < KK) ? f2b(Wq[kcol * PC + c]) : (ushort)0;
  }
}

// ---------------- Kernel 3: PARALLEL-k attention (unchanged)
__global__ __launch_bounds__(256) void k_attn2(
    const int* __restrict__ nbr_idx, const int* __restrict__ nbr_mask,
    const ushort* __restrict__ zc16,
    const float* __restrict__ Wpos, const float* __restrict__ bpos,
    const float* __restrict__ Wq, const float* __restrict__ bq,
    const float* __restrict__ proj, float* __restrict__ attn, int N)
{
  int tid = threadIdx.x;
  int wv = tid >> 6, lane = tid & 63;
  int half = lane >> 5, l = lane & 31;
  int n = blockIdx.x * 8 + wv * 2 + half;
  bool vok = (n < N);
  int j = -1;
  if (vok && l < KK) {
    if (nbr_mask[(size_t)n * KK + l]) j = nbr_idx[(size_t)n * KK + l];
  }
  int cx = 0, cy = 0, cz = 0;
  if (vok) {
    uint2 cd = *(const uint2*)(zc16 + (size_t)n * 32);
    cx = (int)(cd.x & 0xffffu); cy = (int)(cd.x >> 16); cz = (int)(cd.y & 0xffffu);
  }
  float qc = 0.f;
  if (j >= 0) {
    uint2 cj = *(const uint2*)(zc16 + (size_t)j * 32);
    float z = b2f(zc16[(size_t)j * 32 + 4 + l]);
    float rx = (float)((int)(cj.x & 0xffffu) - cx);
    float ry = (float)((int)(cj.x >> 16) - cy);
    float rz = (float)((int)(cj.y & 0xffffu) - cz);
    float t = 0.f;
    #pragma unroll
    for (int c4 = 0; c4 < 16; ++c4) {
      float4 w0 = *(const float4*)(Wpos + c4 * 4);
      float4 w1 = *(const float4*)(Wpos + 64 + c4 * 4);
      float4 w2 = *(const float4*)(Wpos + 128 + c4 * 4);
      float4 bp = *(const float4*)(bpos + c4 * 4);
      float4 wq = *(const float4*)(Wq + (size_t)l * PC + c4 * 4);
      t += fmaxf(rx * w0.x + ry * w1.x + rz * w2.x + bp.x, 0.f) * wq.x;
      t += fmaxf(rx * w0.y + ry * w1.y + rz * w2.y + bp.y, 0.f) * wq.y;
      t += fmaxf(rx * w0.z + ry * w1.z + rz * w2.z + bp.z, 0.f) * wq.z;
      t += fmaxf(rx * w0.w + ry * w1.w + rz * w2.w + bp.w, 0.f) * wq.w;
    }
    qc = z + t;
  }
  qc += __shfl_xor(qc, 1); qc += __shfl_xor(qc, 2); qc += __shfl_xor(qc, 4);
  qc += __shfl_xor(qc, 8); qc += __shfl_xor(qc, 16);
  if (vok && l == 0) {
    float q = fmaxf(qc + bq[0], 0.f);
    float lg[4], mx = -1e30f;
    #pragma unroll
    for (int m = 0; m < 4; ++m) { lg[m] = q * proj[m] * 0.1f; mx = fmaxf(mx, lg[m]); }
    float s = 0.f;
    #pragma unroll
    for (int m = 0; m < 4; ++m) { lg[m] = __expf(lg[m] - mx); s += lg[m]; }
    float inv = 1.f / s;
    #pragma unroll
    for (int m = 0; m < 4; ++m) attn[(size_t)n * 4 + m] = lg[m] * inv;
  }
}

// ---------------- Kernel 4 (R18): gathered GEMM, BM=64, 4 waves (R16 geometry),
// TWO neighbors per iteration: 14 barriers instead of 27, 64 MFMAs per wave per
// barrier. Issue order: bf(kn0) -> bf(kn1) -> commit staged pair -> gathers(p+2)
// -> MFMA kn0 (vmcnt leaves bf1+gathers) -> MFMA kn1 (leaves gathers) -> barrier.
__global__ __launch_bounds__(256) void k_code(
    const ushort* __restrict__ v, const int* __restrict__ nbr_idx, const int* __restrict__ nbr_mask,
    const ushort* __restrict__ Bp, const float* __restrict__ attn,
    const float* __restrict__ xf, const ushort* __restrict__ Wdp, const float* __restrict__ bd,
    const float* __restrict__ bcode, float* __restrict__ out, int N)
{
  const int tid = threadIdx.x;
  const int lane = tid & 63, w = tid >> 6;
  const int base = blockIdx.x * 64;

  __shared__ __align__(16) union SM {
    struct { ushort As[2][2][4096]; int jm[64][KK]; } g;   // 32K + 6.9K = 38.9 KB
    struct { ushort xfb[64][40]; } e;                      // 5.1 KB
  } sm;

  for (int i = tid; i < 64 * KK; i += 256) {
    int r = i / KK, k = i % KK;
    int n = base + r;
    int val = -1;
    if (n < N && nbr_mask[(size_t)n * KK + k]) val = nbr_idx[(size_t)n * KK + k];
    sm.g.jm[r][k] = val;
  }

  const int r0 = tid >> 3, cc0 = tid & 7;
  const int r1 = r0 + 32;
  const int sc0 = cc0 ^ (r0 & 7), sc1 = cc0 ^ (r1 & 7);

  __syncthreads();  // jm ready

  // prologue: pair0 (kn 0,1) -> As[0]; pair1 (kn 2,3) -> regs
  uint4 Re0 = make_uint4(0u,0u,0u,0u), Re1 = Re0, Ro0 = Re0, Ro1 = Re0;
  {
    int ja = sm.g.jm[r0][0], jb = sm.g.jm[r1][0];
    int jc = sm.g.jm[r0][1], jd = sm.g.jm[r1][1];
    uint4 p00 = make_uint4(0u,0u,0u,0u), p01 = p00, p10 = p00, p11 = p00;
    if (ja >= 0) p00 = *(const uint4*)(v + (size_t)ja * PC + cc0 * 8);
    if (jb >= 0) p01 = *(const uint4*)(v + (size_t)jb * PC + cc0 * 8);
    if (jc >= 0) p10 = *(const uint4*)(v + (size_t)jc * PC + cc0 * 8);
    if (jd >= 0) p11 = *(const uint4*)(v + (size_t)jd * PC + cc0 * 8);
    int je = sm.g.jm[r0][2], jf = sm.g.jm[r1][2];
    int jg = sm.g.jm[r0][3], jh = sm.g.jm[r1][3];
    if (je >= 0) Re0 = *(const uint4*)(v + (size_t)je * PC + cc0 * 8);
    if (jf >= 0) Re1 = *(const uint4*)(v + (size_t)jf * PC + cc0 * 8);
    if (jg >= 0) Ro0 = *(const uint4*)(v + (size_t)jg * PC + cc0 * 8);
    if (jh >= 0) Ro1 = *(const uint4*)(v + (size_t)jh * PC + cc0 * 8);
    *(uint4*)(&sm.g.As[0][0][r0 * 64 + sc0 * 8]) = p00;
    *(uint4*)(&sm.g.As[0][0][r1 * 64 + sc1 * 8]) = p01;
    *(uint4*)(&sm.g.As[0][1][r0 * 64 + sc0 * 8]) = p10;
    *(uint4*)(&sm.g.As[0][1][r1 * 64 + sc1 * 8]) = p11;
  }
  __syncthreads();

  f32x4 acc[4][4] = {};
  // col = nt*64 + w*16 + (lane&15)  -> nt stride = 512 ushorts
  const ushort* bbase = Bp + (size_t)(lane >> 4) * 2048 + (size_t)((w << 4) + (lane & 15)) * 8;

  const int NP = (KK + 1) / 2;   // 14 (pair 13 has only kn=26)
  int cur = 0, nx = 1;
  for (int p = 0; p < NP; ++p) {
    const int kn0 = 2 * p, kn1 = kn0 + 1;
    // (1) B fragments for kn0 then kn1 — issued FIRST
    v8s bfA0[4], bfA1[4], bfB0[4], bfB1[4];
    {
      const ushort* bb0 = bbase + (size_t)(8 * kn0) * 2048;
      const ushort* bb1 = bb0 + 4 * 2048;
      #pragma unroll
      for (int nt = 0; nt < 4; ++nt) {
        bfA0[nt] = *(const v8s*)(bb0 + nt * 512);
        bfA1[nt] = *(const v8s*)(bb1 + nt * 512);
      }
    }
    if (kn1 < KK) {
      const ushort* bb0 = bbase + (size_t)(8 * kn1) * 2048;
      const ushort* bb1 = bb0 + 4 * 2048;
      #pragma unroll
      for (int nt = 0; nt < 4; ++nt) {
        bfB0[nt] = *(const v8s*)(bb0 + nt * 512);
        bfB1[nt] = *(const v8s*)(bb1 + nt * 512);
      }
    }
    // (2) EARLY COMMIT: pair p+1 (in flight since last iteration) -> As[nx]
    if (p + 1 < NP) {
      *(uint4*)(&sm.g.As[nx][0][r0 * 64 + sc0 * 8]) = Re0;
      *(uint4*)(&sm.g.As[nx][0][r1 * 64 + sc1 * 8]) = Re1;
      *(uint4*)(&sm.g.As[nx][1][r0 * 64 + sc0 * 8]) = Ro0;
      *(uint4*)(&sm.g.As[nx][1][r1 * 64 + sc1 * 8]) = Ro1;
    }
    // (3) issue gathers for pair p+2 -> regs; stay outstanding across barrier
    Re0 = make_uint4(0u,0u,0u,0u); Re1 = Re0; Ro0 = Re0; Ro1 = Re0;
    if (p + 2 < NP) {
      int ke = 2 * (p + 2), ko = ke + 1;
      int ja = sm.g.jm[r0][ke], jb = sm.g.jm[r1][ke];
      if (ja >= 0) Re0 = *(const uint4*)(v + (size_t)ja * PC + cc0 * 8);
      if (jb >= 0) Re1 = *(const uint4*)(v + (size_t)jb * PC + cc0 * 8);
      if (ko < KK) {
        int jc = sm.g.jm[r0][ko], jd = sm.g.jm[r1][ko];
        if (jc >= 0) Ro0 = *(const uint4*)(v + (size_t)jc * PC + cc0 * 8);
        if (jd >= 0) Ro1 = *(const uint4*)(v + (size_t)jd * PC + cc0 * 8);
      }
    }
    // (4) MFMA kn0 on As[cur][0]
    #pragma unroll
    for (int s2 = 0; s2 < 2; ++s2) {
      v8s af[4];
      const int cc = s2 * 4 + (lane >> 4);
      #pragma unroll
      for (int mt = 0; mt < 4; ++mt) {
        const int r = mt * 16 + (lane & 15);
        const int sc = cc ^ (r & 7);
        af[mt] = *(const v8s*)(&sm.g.As[cur][0][r * 64 + sc * 8]);
      }
      #pragma unroll
      for (int mt = 0; mt < 4; ++mt)
        #pragma unroll
        for (int nt = 0; nt < 4; ++nt)
          acc[mt][nt] = __builtin_amdgcn_mfma_f32_16x16x32_bf16(
              af[mt], (s2 ? bfA1[nt] : bfA0[nt]), acc[mt][nt], 0, 0, 0);
    }
    // (5) MFMA kn1 on As[cur][1]
    if (kn1 < KK) {
      #pragma unroll
      for (int s2 = 0; s2 < 2; ++s2) {
        v8s af[4];
        const int cc = s2 * 4 + (lane >> 4);
        #pragma unroll
        for (int mt = 0; mt < 4; ++mt) {
          const int r = mt * 16 + (lane & 15);
          const int sc = cc ^ (r & 7);
          af[mt] = *(const v8s*)(&sm.g.As[cur][1][r * 64 + sc * 8]);
        }
        #pragma unroll
        for (int mt = 0; mt < 4; ++mt)
          #pragma unroll
          for (int nt = 0; nt < 4; ++nt)
            acc[mt][nt] = __builtin_amdgcn_mfma_f32_16x16x32_bf16(
                af[mt], (s2 ? bfB1[nt] : bfB0[nt]), acc[mt][nt], 0, 0, 0);
      }
    }
    __syncthreads();
    cur ^= 1; nx ^= 1;
  }

  // ---- epilogue: per-lane m-sum + MFMA residual (R16, unchanged)
  for (int i2 = tid; i2 < 2048; i2 += 256) {
    int r = i2 >> 5, c = i2 & 31;
    int n = base + r;
    sm.e.xfb[r][c] = (n < N) ? f2b(xf[(size_t)n * INC + c]) : (ushort)0;
  }
  __syncthreads();

  const int ln = lane & 15, grp = lane >> 4;
  const int d = (w << 4) + ln;
  v8s wdf = *(const v8s*)(Wdp + (size_t)d * 32 + grp * 8);
  f32x4 res[4];
  #pragma unroll
  for (int mt = 0; mt < 4; ++mt) {
    v8s af = *(const v8s*)(&sm.e.xfb[mt * 16 + ln][grp * 8]);
    f32x4 z = {0.f, 0.f, 0.f, 0.f};
    res[mt] = __builtin_amdgcn_mfma_f32_16x16x32_bf16(af, wdf, z, 0, 0, 0);
  }
  float bcv[4];
  #pragma unroll
  for (int nt = 0; nt < 4; ++nt) bcv[nt] = bcode[nt * PC + d];
  const float bdv = bd[d];
  #pragma unroll
  for (int mt = 0; mt < 4; ++mt) {
    #pragma unroll
    for (int i = 0; i < 4; ++i) {
      int row = mt * 16 + grp * 4 + i;
      int n = base + row;
      if (n < N) {
        float4 a4 = *(const float4*)(attn + (size_t)n * 4);
        float val = res[mt][i] + bdv;
        val += a4.x * fmaxf(acc[mt][0][i] + bcv[0], 0.f);
        val += a4.y * fmaxf(acc[mt][1][i] + bcv[1], 0.f);
        val += a4.z * fmaxf(acc[mt][2][i] + bcv[2], 0.f);
        val += a4.w * fmaxf(acc[mt][3][i] + bcv[3], 0.f);
        out[(size_t)n * PC + d] = fmaxf(val, 0.f);
      }
    }
  }
}

extern "C" void kernel_launch(void* const* d_in, const int* in_sizes, int n_in,
                              void* d_out, int out_size, void* d_ws, size_t ws_size,
                              hipStream_t stream)
{
  const float* xf     = (const float*)d_in[0];
  const int* nbr_idx  = (const int*)d_in[1];
  const int* nbr_mask = (const int*)d_in[2];
  const int* coords   = (const int*)d_in[3];
  const float* Wt     = (const float*)d_in[4];
  const float* bt     = (const float*)d_in[5];
  const float* Wd     = (const float*)d_in[6];
  const float* bd     = (const float*)d_in[7];
  const float* Wpos   = (const float*)d_in[8];
  const float* bpos   = (const float*)d_in[9];
  const float* Wq     = (const float*)d_in[10];
  const float* bq     = (const float*)d_in[11];
  const float* proj   = (const float*)d_in[12];
  const float* Wv     = (const float*)d_in[13];
  const float* bv     = (const float*)d_in[14];
  const float* Wcode  = (const float*)d_in[15];
  const float* bcode  = (const float*)d_in[16];
  float* out = (float*)d_out;

  int N = in_sizes[0] / INC;

  char* ws = (char*)d_ws;
  size_t off = 0;
  auto alloc = [&](size_t bytes) {
    off = (off + 255) & ~(size_t)255;
    void* p = ws + off;
    off += bytes;
    return p;
  };
  ushort* v_ws  = (ushort*)alloc((size_t)N * PC * 2);
  ushort* zc_ws = (ushort*)alloc((size_t)N * 32 * 2);
  float*  a_ws  = (float*)alloc((size_t)N * 4 * 4);
  ushort* B_ws  = (ushort*)alloc((size_t)54 * 4 * 256 * 8 * 2);
  ushort* D_ws  = (ushort*)alloc((size_t)2048 * 2);
  ushort* T_ws  = (ushort*)alloc((size_t)2048 * 2);
  ushort* V2_ws = (ushort*)alloc((size_t)4096 * 2);
  ushort* Q_ws  = (ushort*)alloc((size_t)2048 * 2);
  (void)ws_size;

  hipLaunchKernelGGL(k_prepBD, dim3(1768), dim3(256), 0, stream,
                     Wcode, Wd, Wt, Wv, Wq, B_ws, D_ws, T_ws, V2_ws, Q_ws);
  hipLaunchKernelGGL(k_prep2, dim3((N + 63) / 64), dim3(256), 0, stream,
                     xf, T_ws, bt, V2_ws, bv, Q_ws, coords, v_ws, zc_ws, N);
  hipLaunchKernelGGL(k_attn2, dim3((N + 7) / 8), dim3(256), 0, stream,
                     nbr_idx, nbr_mask, zc_ws, Wpos, bpos, Wq, bq, proj, a_ws, N);
  hipLaunchKernelGGL(k_code, dim3((N + 63) / 64), dim3(256), 0, stream,
                     v_ws, nbr_idx, nbr_mask, B_ws, a_ws, xf, D_ws, bd, bcode, out, N);
}

// Round 19
// 174.832 us; speedup vs baseline: 1.3871x; 1.1173x over previous
//
#include <hip/hip_runtime.h>

#define KK 27
#define INC 32
#define PC 64

typedef __attribute__((ext_vector_type(8))) short v8s;
typedef __attribute__((ext_vector_type(4))) float f32x4;

static __device__ __forceinline__ float b2f(ushort u) {
  union { float f; unsigned int i; } x; x.i = ((unsigned int)u) << 16; return x.f;
}
static __device__ __forceinline__ ushort f2b(float f) {
  union { float f; unsigned int i; } x; x.f = f;
  unsigned int u = x.i;
  unsigned int r = (u + 0x7FFFu + ((u >> 16) & 1u)) >> 16;
  return (ushort)r;
}

// ---------------- Kernel 1 (R16): MFMA-based prep. 64 voxels/block, 4 waves.
__global__ __launch_bounds__(256) void k_prep2(
    const float* __restrict__ xf, const ushort* __restrict__ Wtp, const float* __restrict__ bt,
    const ushort* __restrict__ Wvp, const float* __restrict__ bv,
    const ushort* __restrict__ Wqp, const int* __restrict__ coords,
    ushort* __restrict__ v, ushort* __restrict__ zc16, int N)
{
  const int tid = threadIdx.x;
  const int lane = tid & 63, w = tid >> 6;
  const int ln = lane & 15, grp = lane >> 4;
  const int base = blockIdx.x * 64;

  __shared__ __align__(16) ushort xfb[64][40];
  __shared__ __align__(16) ushort xb[64][72];

  {
    int r = tid >> 2, c0 = (tid & 3) * 8;
    int n = base + r;
    v8s d = {0,0,0,0,0,0,0,0};
    if (n < N) {
      float4 f0 = *(const float4*)(xf + (size_t)n * INC + c0);
      float4 f1 = *(const float4*)(xf + (size_t)n * INC + c0 + 4);
      d[0] = (short)f2b(f0.x); d[1] = (short)f2b(f0.y);
      d[2] = (short)f2b(f0.z); d[3] = (short)f2b(f0.w);
      d[4] = (short)f2b(f1.x); d[5] = (short)f2b(f1.y);
      d[6] = (short)f2b(f1.z); d[7] = (short)f2b(f1.w);
    }
    *(v8s*)(&xfb[r][c0]) = d;
  }
  if (tid < 64) {
    int n = base + tid;
    if (n < N) {
      ushort* row = zc16 + (size_t)n * 32;
      row[0] = (ushort)coords[n * 3 + 0];
      row[1] = (ushort)coords[n * 3 + 1];
      row[2] = (ushort)coords[n * 3 + 2];
      row[3] = 0;
    }
  }
  __syncthreads();

  const int d = w * 16 + ln;
  {
    v8s wtf = *(const v8s*)(Wtp + (size_t)d * 32 + grp * 8);
    float btv = bt[d];
    #pragma unroll
    for (int mt = 0; mt < 4; ++mt) {
      v8s af = *(const v8s*)(&xfb[mt * 16 + ln][grp * 8]);
      f32x4 z4 = {0.f, 0.f, 0.f, 0.f};
      f32x4 acc = __builtin_amdgcn_mfma_f32_16x16x32_bf16(af, wtf, z4, 0, 0, 0);
      #pragma unroll
      for (int i = 0; i < 4; ++i) {
        int row = mt * 16 + grp * 4 + i;
        xb[row][d] = f2b(fmaxf(acc[i] + btv, 0.f));
      }
    }
  }
  __syncthreads();

  {
    v8s wv0 = *(const v8s*)(Wvp + (size_t)d * 64 + grp * 8);
    v8s wv1 = *(const v8s*)(Wvp + (size_t)d * 64 + 32 + grp * 8);
    float bvv = bv[d];
    #pragma unroll
    for (int mt = 0; mt < 4; ++mt) {
      v8s a0 = *(const v8s*)(&xb[mt * 16 + ln][grp * 8]);
      v8s a1 = *(const v8s*)(&xb[mt * 16 + ln][32 + grp * 8]);
      f32x4 acc = {0.f, 0.f, 0.f, 0.f};
      acc = __builtin_amdgcn_mfma_f32_16x16x32_bf16(a0, wv0, acc, 0, 0, 0);
      acc = __builtin_amdgcn_mfma_f32_16x16x32_bf16(a1, wv1, acc, 0, 0, 0);
      #pragma unroll
      for (int i = 0; i < 4; ++i) {
        int row = mt * 16 + grp * 4 + i;
        int n = base + row;
        if (n < N) v[(size_t)n * PC + d] = f2b(fmaxf(acc[i] + bvv, 0.f));
      }
    }
  }

  {
    const int kcol = (w & 1) * 16 + ln;
    v8s wq0 = *(const v8s*)(Wqp + (size_t)kcol * 64 + grp * 8);
    v8s wq1 = *(const v8s*)(Wqp + (size_t)kcol * 64 + 32 + grp * 8);
    #pragma unroll
    for (int mtt = 0; mtt < 2; ++mtt) {
      int mt = 2 * (w >> 1) + mtt;
      v8s a0 = *(const v8s*)(&xb[mt * 16 + ln][grp * 8]);
      v8s a1 = *(const v8s*)(&xb[mt * 16 + ln][32 + grp * 8]);
      f32x4 acc = {0.f, 0.f, 0.f, 0.f};
      acc = __builtin_amdgcn_mfma_f32_16x16x32_bf16(a0, wq0, acc, 0, 0, 0);
      acc = __builtin_amdgcn_mfma_f32_16x16x32_bf16(a1, wq1, acc, 0, 0, 0);
      if (kcol < KK) {
        #pragma unroll
        for (int i = 0; i < 4; ++i) {
          int row = mt * 16 + grp * 4 + i;
          int n = base + row;
          if (n < N) zc16[(size_t)n * 32 + 4 + kcol] = f2b(acc[i]);
        }
      }
    }
  }
}

// ---------------- Kernel 2: repack weights (unchanged)
__global__ __launch_bounds__(256) void k_prepBD(
    const float* __restrict__ Wcode, const float* __restrict__ Wd,
    const float* __restrict__ Wt, const float* __restrict__ Wv, const float* __restrict__ Wq,
    ushort* __restrict__ Bp, ushort* __restrict__ Wdp,
    ushort* __restrict__ Wtp, ushort* __restrict__ Wvp, ushort* __restrict__ Wqp)
{
  int bid = blockIdx.x;
  if (bid < 1728) {
    int i = bid * 256 + threadIdx.x;
    int j = i & 7;
    int col = (i >> 3) & 255;
    int kg = (i >> 11) & 3;
    int s = i >> 13;
    int k = s * 32 + kg * 8 + j;
    int m = col >> 6, dd = col & 63;
    int knbr = k >> 6, c = k & 63;
    Bp[i] = f2b(Wcode[(((m * KK + knbr) * 64) + c) * 64 + dd]);
  } else if (bid < 1736) {
    int i = (bid - 1728) * 256 + threadIdx.x;
    int col = i >> 5, k = i & 31;
    Wdp[i] = f2b(Wd[k * PC + col]);
  } else if (bid < 1744) {
    int i = (bid - 1736) * 256 + threadIdx.x;
    int col = i >> 5, k = i & 31;
    Wtp[i] = f2b(Wt[k * PC + col]);
  } else if (bid < 1760) {
    int i = (bid - 1744) * 256 + threadIdx.x;
    int col = i >> 6, k = i & 63;
    Wvp[i] = f2b(Wv[k * PC + col]);
  } else {
    int i = (bid - 1760) * 256 + threadIdx.x;
    int kcol = i >> 6, c = i & 63;
    Wqp[i] = (kcol < KK) ? f2b(Wq[kcol * PC + c]) : (ushort)0;
  }
}

// ---------------- Kernel 3: PARALLEL-k attention (unchanged)
__global__ __launch_bounds__(256) void k_attn2(
    const int* __restrict__ nbr_idx, const int* __restrict__ nbr_mask,
    const ushort* __restrict__ zc16,
    const float* __restrict__ Wpos, const float* __restrict__ bpos,
    const float* __restrict__ Wq, const float* __restrict__ bq,
    const float* __restrict__ proj, float* __restrict__ attn, int N)
{
  int tid = threadIdx.x;
  int wv = tid >> 6, lane = tid & 63;
  int half = lane >> 5, l = lane & 31;
  int n = blockIdx.x * 8 + wv * 2 + half;
  bool vok = (n < N);
  int j = -1;
  if (vok && l < KK) {
    if (nbr_mask[(size_t)n * KK + l]) j = nbr_idx[(size_t)n * KK + l];
  }
  int cx = 0, cy = 0, cz = 0;
  if (vok) {
    uint2 cd = *(const uint2*)(zc16 + (size_t)n * 32);
    cx = (int)(cd.x & 0xffffu); cy = (int)(cd.x >> 16); cz = (int)(cd.y & 0xffffu);
  }
  float qc = 0.f;
  if (j >= 0) {
    uint2 cj = *(const uint2*)(zc16 + (size_t)j * 32);
    float z = b2f(zc16[(size_t)j * 32 + 4 + l]);
    float rx = (float)((int)(cj.x & 0xffffu) - cx);
    float ry = (float)((int)(cj.x >> 16) - cy);
    float rz = (float)((int)(cj.y & 0xffffu) - cz);
    float t = 0.f;
    #pragma unroll
    for (int c4 = 0; c4 < 16; ++c4) {
      float4 w0 = *(const float4*)(Wpos + c4 * 4);
      float4 w1 = *(const float4*)(Wpos + 64 + c4 * 4);
      float4 w2 = *(const float4*)(Wpos + 128 + c4 * 4);
      float4 bp = *(const float4*)(bpos + c4 * 4);
      float4 wq = *(const float4*)(Wq + (size_t)l * PC + c4 * 4);
      t += fmaxf(rx * w0.x + ry * w1.x + rz * w2.x + bp.x, 0.f) * wq.x;
      t += fmaxf(rx * w0.y + ry * w1.y + rz * w2.y + bp.y, 0.f) * wq.y;
      t += fmaxf(rx * w0.z + ry * w1.z + rz * w2.z + bp.z, 0.f) * wq.z;
      t += fmaxf(rx * w0.w + ry * w1.w + rz * w2.w + bp.w, 0.f) * wq.w;
    }
    qc = z + t;
  }
  qc += __shfl_xor(qc, 1); qc += __shfl_xor(qc, 2); qc += __shfl_xor(qc, 4);
  qc += __shfl_xor(qc, 8); qc += __shfl_xor(qc, 16);
  if (vok && l == 0) {
    float q = fmaxf(qc + bq[0], 0.f);
    float lg[4], mx = -1e30f;
    #pragma unroll
    for (int m = 0; m < 4; ++m) { lg[m] = q * proj[m] * 0.1f; mx = fmaxf(mx, lg[m]); }
    float s = 0.f;
    #pragma unroll
    for (int m = 0; m < 4; ++m) { lg[m] = __expf(lg[m] - mx); s += lg[m]; }
    float inv = 1.f / s;
    #pragma unroll
    for (int m = 0; m < 4; ++m) attn[(size_t)n * 4 + m] = lg[m] * inv;
  }
}

// ---------------- Kernel 4 (R19): R16/R9 core verbatim + __launch_bounds__(256,4)
// forcing arch VGPR <= 64 so combined (arch+64 AGPR acc) <= 128 -> 4 waves/SIMD.
__global__ __launch_bounds__(256, 4) void k_code(
    const ushort* __restrict__ v, const int* __restrict__ nbr_idx, const int* __restrict__ nbr_mask,
    const ushort* __restrict__ Bp, const float* __restrict__ attn,
    const float* __restrict__ xf, const ushort* __restrict__ Wdp, const float* __restrict__ bd,
    const float* __restrict__ bcode, float* __restrict__ out, int N)
{
  const int tid = threadIdx.x;
  const int lane = tid & 63, w = tid >> 6;
  const int base = blockIdx.x * 64;

  __shared__ __align__(16) union SM {
    struct { ushort As[3][4096]; int jm[64][KK]; } g;   // GEMM phase (31.5 KB)
    struct { ushort xfb[64][40]; } e;                   // epilogue (5.1 KB)
  } sm;

  for (int i = tid; i < 64 * KK; i += 256) {
    int r = i / KK, k = i % KK;
    int n = base + r;
    int val = -1;
    if (n < N && nbr_mask[(size_t)n * KK + k]) val = nbr_idx[(size_t)n * KK + k];
    sm.g.jm[r][k] = val;
  }

  const int r0 = tid >> 3, cc0 = tid & 7;
  const int r1 = r0 + 32,  cc1 = cc0;
  const int sc0 = cc0 ^ (r0 & 7), sc1 = cc1 ^ (r1 & 7);

  __syncthreads();  // jm ready

  uint4 R0 = make_uint4(0u,0u,0u,0u), R1 = R0;
  {
    int j0 = sm.g.jm[r0][0], j1 = sm.g.jm[r1][0];
    uint4 p0 = make_uint4(0u, 0u, 0u, 0u), p1 = p0;
    if (j0 >= 0) p0 = *(const uint4*)(v + (size_t)j0 * PC + cc0 * 8);
    if (j1 >= 0) p1 = *(const uint4*)(v + (size_t)j1 * PC + cc1 * 8);
    int jc = sm.g.jm[r0][1], jd = sm.g.jm[r1][1];
    if (jc >= 0) R0 = *(const uint4*)(v + (size_t)jc * PC + cc0 * 8);
    if (jd >= 0) R1 = *(const uint4*)(v + (size_t)jd * PC + cc1 * 8);
    *(uint4*)(&sm.g.As[0][r0 * 64 + sc0 * 8]) = p0;
    *(uint4*)(&sm.g.As[0][r1 * 64 + sc1 * 8]) = p1;
  }
  __syncthreads();

  f32x4 acc[4][4] = {};
  const ushort* bbase = Bp + (size_t)(lane >> 4) * 2048 + (size_t)((w << 4) + (lane & 15)) * 8;

  int cur = 0, nx = 1;
  for (int kn = 0; kn < KK; ++kn) {
    v8s bf0[4], bf1[4];
    {
      const ushort* bb0 = bbase + (size_t)(8 * kn) * 2048;
      const ushort* bb1 = bb0 + 4 * 2048;
      #pragma unroll
      for (int nt = 0; nt < 4; ++nt) {
        bf0[nt] = *(const v8s*)(bb0 + nt * 512);
        bf1[nt] = *(const v8s*)(bb1 + nt * 512);
      }
    }
    if (kn + 1 < KK) {
      *(uint4*)(&sm.g.As[nx][r0 * 64 + sc0 * 8]) = R0;
      *(uint4*)(&sm.g.As[nx][r1 * 64 + sc1 * 8]) = R1;
    }
    R0 = make_uint4(0u,0u,0u,0u); R1 = R0;
    if (kn + 2 < KK) {
      int j0 = sm.g.jm[r0][kn + 2], j1 = sm.g.jm[r1][kn + 2];
      if (j0 >= 0) R0 = *(const uint4*)(v + (size_t)j0 * PC + cc0 * 8);
      if (j1 >= 0) R1 = *(const uint4*)(v + (size_t)j1 * PC + cc1 * 8);
    }
    #pragma unroll
    for (int s2 = 0; s2 < 2; ++s2) {
      v8s af[4];
      const int cc = s2 * 4 + (lane >> 4);
      #pragma unroll
      for (int mt = 0; mt < 4; ++mt) {
        const int r = mt * 16 + (lane & 15);
        const int sc = cc ^ (r & 7);
        af[mt] = *(const v8s*)(&sm.g.As[cur][r * 64 + sc * 8]);
      }
      #pragma unroll
      for (int mt = 0; mt < 4; ++mt)
        #pragma unroll
        for (int nt = 0; nt < 4; ++nt)
          acc[mt][nt] = __builtin_amdgcn_mfma_f32_16x16x32_bf16(
              af[mt], (s2 ? bf1[nt] : bf0[nt]), acc[mt][nt], 0, 0, 0);
    }
    __syncthreads();
    cur = nx; nx = (nx == 2) ? 0 : nx + 1;
  }

  for (int i2 = tid; i2 < 2048; i2 += 256) {
    int r = i2 >> 5, c = i2 & 31;
    int n = base + r;
    sm.e.xfb[r][c] = (n < N) ? f2b(xf[(size_t)n * INC + c]) : (ushort)0;
  }
  __syncthreads();

  const int ln = lane & 15, grp = lane >> 4;
  const int d = (w << 4) + ln;
  v8s wdf = *(const v8s*)(Wdp + (size_t)d * 32 + grp * 8);
  f32x4 res[4];
  #pragma unroll
  for (int mt = 0; mt < 4; ++mt) {
    v8s af = *(const v8s*)(&sm.e.xfb[mt * 16 + ln][grp * 8]);
    f32x4 z = {0.f, 0.f, 0.f, 0.f};
    res[mt] = __builtin_amdgcn_mfma_f32_16x16x32_bf16(af, wdf, z, 0, 0, 0);
  }
  float bcv[4];
  #pragma unroll
  for (int nt = 0; nt < 4; ++nt) bcv[nt] = bcode[nt * PC + d];
  const float bdv = bd[d];
  #pragma unroll
  for (int mt = 0; mt < 4; ++mt) {
    #pragma unroll
    for (int i = 0; i < 4; ++i) {
      int row = mt * 16 + grp * 4 + i;
      int n = base + row;
      if (n < N) {
        float4 a4 = *(const float4*)(attn + (size_t)n * 4);
        float val = res[mt][i] + bdv;
        val += a4.x * fmaxf(acc[mt][0][i] + bcv[0], 0.f);
        val += a4.y * fmaxf(acc[mt][1][i] + bcv[1], 0.f);
        val += a4.z * fmaxf(acc[mt][2][i] + bcv[2], 0.f);
        val += a4.w * fmaxf(acc[mt][3][i] + bcv[3], 0.f);
        out[(size_t)n * PC + d] = fmaxf(val, 0.f);
      }
    }
  }
}

extern "C" void kernel_launch(void* const* d_in, const int* in_sizes, int n_in,
                              void* d_out, int out_size, void* d_ws, size_t ws_size,
                              hipStream_t stream)
{
  const float* xf     = (const float*)d_in[0];
  const int* nbr_idx  = (const int*)d_in[1];
  const int* nbr_mask = (const int*)d_in[2];
  const int* coords   = (const int*)d_in[3];
  const float* Wt     = (const float*)d_in[4];
  const float* bt     = (const float*)d_in[5];
  const float* Wd     = (const float*)d_in[6];
  const float* bd     = (const float*)d_in[7];
  const float* Wpos   = (const float*)d_in[8];
  const float* bpos   = (const float*)d_in[9];
  const float* Wq     = (const float*)d_in[10];
  const float* bq     = (const float*)d_in[11];
  const float* proj   = (const float*)d_in[12];
  const float* Wv     = (const float*)d_in[13];
  const float* bv     = (const float*)d_in[14];
  const float* Wcode  = (const float*)d_in[15];
  const float* bcode  = (const float*)d_in[16];
  float* out = (float*)d_out;

  int N = in_sizes[0] / INC;

  char* ws = (char*)d_ws;
  size_t off = 0;
  auto alloc = [&](size_t bytes) {
    off = (off + 255) & ~(size_t)255;
    void* p = ws + off;
    off += bytes;
    return p;
  };
  ushort* v_ws  = (ushort*)alloc((size_t)N * PC * 2);
  ushort* zc_ws = (ushort*)alloc((size_t)N * 32 * 2);
  float*  a_ws  = (float*)alloc((size_t)N * 4 * 4);
  ushort* B_ws  = (ushort*)alloc((size_t)54 * 4 * 256 * 8 * 2);
  ushort* D_ws  = (ushort*)alloc((size_t)2048 * 2);
  ushort* T_ws  = (ushort*)alloc((size_t)2048 * 2);
  ushort* V2_ws = (ushort*)alloc((size_t)4096 * 2);
  ushort* Q_ws  = (ushort*)alloc((size_t)2048 * 2);
  (void)ws_size;

  hipLaunchKernelGGL(k_prepBD, dim3(1768), dim3(256), 0, stream,
                     Wcode, Wd, Wt, Wv, Wq, B_ws, D_ws, T_ws, V2_ws, Q_ws);
  hipLaunchKernelGGL(k_prep2, dim3((N + 63) / 64), dim3(256), 0, stream,
                     xf, T_ws, bt, V2_ws, bv, Q_ws, coords, v_ws, zc_ws, N);
  hipLaunchKernelGGL(k_attn2, dim3((N + 7) / 8), dim3(256), 0, stream,
                     nbr_idx, nbr_mask, zc_ws, Wpos, bpos, Wq, bq, proj, a_ws, N);
  hipLaunchKernelGGL(k_code, dim3((N + 63) / 64), dim3(256), 0, stream,
                     v_ws, nbr_idx, nbr_mask, B_ws, a_ws, xf, D_ws, bd, bcode, out, N);
}

// Round 20
// 174.799 us; speedup vs baseline: 1.3874x; 1.0002x over previous
//
#include <hip/hip_runtime.h>

#define KK 27
#define INC 32
#define PC 64

typedef __attribute__((ext_vector_type(8))) short v8s;
typedef __attribute__((ext_vector_type(4))) float f32x4;

static __device__ __forceinline__ float b2f(ushort u) {
  union { float f; unsigned int i; } x; x.i = ((unsigned int)u) << 16; return x.f;
}
static __device__ __forceinline__ ushort f2b(float f) {
  union { float f; unsigned int i; } x; x.f = f;
  unsigned int u = x.i;
  unsigned int r = (u + 0x7FFFu + ((u >> 16) & 1u)) >> 16;
  return (ushort)r;
}

// ---------------- Kernel 1 (R16): MFMA-based prep. 64 voxels/block, 4 waves.
__global__ __launch_bounds__(256) void k_prep2(
    const float* __restrict__ xf, const ushort* __restrict__ Wtp, const float* __restrict__ bt,
    const ushort* __restrict__ Wvp, const float* __restrict__ bv,
    const ushort* __restrict__ Wqp, const int* __restrict__ coords,
    ushort* __restrict__ v, ushort* __restrict__ zc16, int N)
{
  const int tid = threadIdx.x;
  const int lane = tid & 63, w = tid >> 6;
  const int ln = lane & 15, grp = lane >> 4;
  const int base = blockIdx.x * 64;

  __shared__ __align__(16) ushort xfb[64][40];
  __shared__ __align__(16) ushort xb[64][72];

  {
    int r = tid >> 2, c0 = (tid & 3) * 8;
    int n = base + r;
    v8s d = {0,0,0,0,0,0,0,0};
    if (n < N) {
      float4 f0 = *(const float4*)(xf + (size_t)n * INC + c0);
      float4 f1 = *(const float4*)(xf + (size_t)n * INC + c0 + 4);
      d[0] = (short)f2b(f0.x); d[1] = (short)f2b(f0.y);
      d[2] = (short)f2b(f0.z); d[3] = (short)f2b(f0.w);
      d[4] = (short)f2b(f1.x); d[5] = (short)f2b(f1.y);
      d[6] = (short)f2b(f1.z); d[7] = (short)f2b(f1.w);
    }
    *(v8s*)(&xfb[r][c0]) = d;
  }
  if (tid < 64) {
    int n = base + tid;
    if (n < N) {
      ushort* row = zc16 + (size_t)n * 32;
      row[0] = (ushort)coords[n * 3 + 0];
      row[1] = (ushort)coords[n * 3 + 1];
      row[2] = (ushort)coords[n * 3 + 2];
      row[3] = 0;
    }
  }
  __syncthreads();

  const int d = w * 16 + ln;
  {
    v8s wtf = *(const v8s*)(Wtp + (size_t)d * 32 + grp * 8);
    float btv = bt[d];
    #pragma unroll
    for (int mt = 0; mt < 4; ++mt) {
      v8s af = *(const v8s*)(&xfb[mt * 16 + ln][grp * 8]);
      f32x4 z4 = {0.f, 0.f, 0.f, 0.f};
      f32x4 acc = __builtin_amdgcn_mfma_f32_16x16x32_bf16(af, wtf, z4, 0, 0, 0);
      #pragma unroll
      for (int i = 0; i < 4; ++i) {
        int row = mt * 16 + grp * 4 + i;
        xb[row][d] = f2b(fmaxf(acc[i] + btv, 0.f));
      }
    }
  }
  __syncthreads();

  {
    v8s wv0 = *(const v8s*)(Wvp + (size_t)d * 64 + grp * 8);
    v8s wv1 = *(const v8s*)(Wvp + (size_t)d * 64 + 32 + grp * 8);
    float bvv = bv[d];
    #pragma unroll
    for (int mt = 0; mt < 4; ++mt) {
      v8s a0 = *(const v8s*)(&xb[mt * 16 + ln][grp * 8]);
      v8s a1 = *(const v8s*)(&xb[mt * 16 + ln][32 + grp * 8]);
      f32x4 acc = {0.f, 0.f, 0.f, 0.f};
      acc = __builtin_amdgcn_mfma_f32_16x16x32_bf16(a0, wv0, acc, 0, 0, 0);
      acc = __builtin_amdgcn_mfma_f32_16x16x32_bf16(a1, wv1, acc, 0, 0, 0);
      #pragma unroll
      for (int i = 0; i < 4; ++i) {
        int row = mt * 16 + grp * 4 + i;
        int n = base + row;
        if (n < N) v[(size_t)n * PC + d] = f2b(fmaxf(acc[i] + bvv, 0.f));
      }
    }
  }

  {
    const int kcol = (w & 1) * 16 + ln;
    v8s wq0 = *(const v8s*)(Wqp + (size_t)kcol * 64 + grp * 8);
    v8s wq1 = *(const v8s*)(Wqp + (size_t)kcol * 64 + 32 + grp * 8);
    #pragma unroll
    for (int mtt = 0; mtt < 2; ++mtt) {
      int mt = 2 * (w >> 1) + mtt;
      v8s a0 = *(const v8s*)(&xb[mt * 16 + ln][grp * 8]);
      v8s a1 = *(const v8s*)(&xb[mt * 16 + ln][32 + grp * 8]);
      f32x4 acc = {0.f, 0.f, 0.f, 0.f};
      acc = __builtin_amdgcn_mfma_f32_16x16x32_bf16(a0, wq0, acc, 0, 0, 0);
      acc = __builtin_amdgcn_mfma_f32_16x16x32_bf16(a1, wq1, acc, 0, 0, 0);
      if (kcol < KK) {
        #pragma unroll
        for (int i = 0; i < 4; ++i) {
          int row = mt * 16 + grp * 4 + i;
          int n = base + row;
          if (n < N) zc16[(size_t)n * 32 + 4 + kcol] = f2b(acc[i]);
        }
      }
    }
  }
}

// ---------------- Kernel 2: repack weights (unchanged)
__global__ __launch_bounds__(256) void k_prepBD(
    const float* __restrict__ Wcode, const float* __restrict__ Wd,
    const float* __restrict__ Wt, const float* __restrict__ Wv, const float* __restrict__ Wq,
    ushort* __restrict__ Bp, ushort* __restrict__ Wdp,
    ushort* __restrict__ Wtp, ushort* __restrict__ Wvp, ushort* __restrict__ Wqp)
{
  int bid = blockIdx.x;
  if (bid < 1728) {
    int i = bid * 256 + threadIdx.x;
    int j = i & 7;
    int col = (i >> 3) & 255;
    int kg = (i >> 11) & 3;
    int s = i >> 13;
    int k = s * 32 + kg * 8 + j;
    int m = col >> 6, dd = col & 63;
    int knbr = k >> 6, c = k & 63;
    Bp[i] = f2b(Wcode[(((m * KK + knbr) * 64) + c) * 64 + dd]);
  } else if (bid < 1736) {
    int i = (bid - 1728) * 256 + threadIdx.x;
    int col = i >> 5, k = i & 31;
    Wdp[i] = f2b(Wd[k * PC + col]);
  } else if (bid < 1744) {
    int i = (bid - 1736) * 256 + threadIdx.x;
    int col = i >> 5, k = i & 31;
    Wtp[i] = f2b(Wt[k * PC + col]);
  } else if (bid < 1760) {
    int i = (bid - 1744) * 256 + threadIdx.x;
    int col = i >> 6, k = i & 63;
    Wvp[i] = f2b(Wv[k * PC + col]);
  } else {
    int i = (bid - 1760) * 256 + threadIdx.x;
    int kcol = i >> 6, c = i & 63;
    Wqp[i] = (kcol < KK) ? f2b(Wq[kcol * PC + c]) : (ushort)0;
  }
}

// ---------------- Kernel 3: PARALLEL-k attention (unchanged)
__global__ __launch_bounds__(256) void k_attn2(
    const int* __restrict__ nbr_idx, const int* __restrict__ nbr_mask,
    const ushort* __restrict__ zc16,
    const float* __restrict__ Wpos, const float* __restrict__ bpos,
    const float* __restrict__ Wq, const float* __restrict__ bq,
    const float* __restrict__ proj, float* __restrict__ attn, int N)
{
  int tid = threadIdx.x;
  int wv = tid >> 6, lane = tid & 63;
  int half = lane >> 5, l = lane & 31;
  int n = blockIdx.x * 8 + wv * 2 + half;
  bool vok = (n < N);
  int j = -1;
  if (vok && l < KK) {
    if (nbr_mask[(size_t)n * KK + l]) j = nbr_idx[(size_t)n * KK + l];
  }
  int cx = 0, cy = 0, cz = 0;
  if (vok) {
    uint2 cd = *(const uint2*)(zc16 + (size_t)n * 32);
    cx = (int)(cd.x & 0xffffu); cy = (int)(cd.x >> 16); cz = (int)(cd.y & 0xffffu);
  }
  float qc = 0.f;
  if (j >= 0) {
    uint2 cj = *(const uint2*)(zc16 + (size_t)j * 32);
    float z = b2f(zc16[(size_t)j * 32 + 4 + l]);
    float rx = (float)((int)(cj.x & 0xffffu) - cx);
    float ry = (float)((int)(cj.x >> 16) - cy);
    float rz = (float)((int)(cj.y & 0xffffu) - cz);
    float t = 0.f;
    #pragma unroll
    for (int c4 = 0; c4 < 16; ++c4) {
      float4 w0 = *(const float4*)(Wpos + c4 * 4);
      float4 w1 = *(const float4*)(Wpos + 64 + c4 * 4);
      float4 w2 = *(const float4*)(Wpos + 128 + c4 * 4);
      float4 bp = *(const float4*)(bpos + c4 * 4);
      float4 wq = *(const float4*)(Wq + (size_t)l * PC + c4 * 4);
      t += fmaxf(rx * w0.x + ry * w1.x + rz * w2.x + bp.x, 0.f) * wq.x;
      t += fmaxf(rx * w0.y + ry * w1.y + rz * w2.y + bp.y, 0.f) * wq.y;
      t += fmaxf(rx * w0.z + ry * w1.z + rz * w2.z + bp.z, 0.f) * wq.z;
      t += fmaxf(rx * w0.w + ry * w1.w + rz * w2.w + bp.w, 0.f) * wq.w;
    }
    qc = z + t;
  }
  qc += __shfl_xor(qc, 1); qc += __shfl_xor(qc, 2); qc += __shfl_xor(qc, 4);
  qc += __shfl_xor(qc, 8); qc += __shfl_xor(qc, 16);
  if (vok && l == 0) {
    float q = fmaxf(qc + bq[0], 0.f);
    float lg[4], mx = -1e30f;
    #pragma unroll
    for (int m = 0; m < 4; ++m) { lg[m] = q * proj[m] * 0.1f; mx = fmaxf(mx, lg[m]); }
    float s = 0.f;
    #pragma unroll
    for (int m = 0; m < 4; ++m) { lg[m] = __expf(lg[m] - mx); s += lg[m]; }
    float inv = 1.f / s;
    #pragma unroll
    for (int m = 0; m < 4; ++m) attn[(size_t)n * 4 + m] = lg[m] * inv;
  }
}

// ---------------- Kernel 4 (R20): R19 core + inline per-mt residual MFMA
// (res computed one tile at a time -> 12 fewer live AGPRs in the epilogue,
// targeting the combined-128 occupancy boundary).
__global__ __launch_bounds__(256, 4) void k_code(
    const ushort* __restrict__ v, const int* __restrict__ nbr_idx, const int* __restrict__ nbr_mask,
    const ushort* __restrict__ Bp, const float* __restrict__ attn,
    const float* __restrict__ xf, const ushort* __restrict__ Wdp, const float* __restrict__ bd,
    const float* __restrict__ bcode, float* __restrict__ out, int N)
{
  const int tid = threadIdx.x;
  const int lane = tid & 63, w = tid >> 6;
  const int base = blockIdx.x * 64;

  __shared__ __align__(16) union SM {
    struct { ushort As[3][4096]; int jm[64][KK]; } g;   // GEMM phase (31.5 KB)
    struct { ushort xfb[64][40]; } e;                   // epilogue (5.1 KB)
  } sm;

  for (int i = tid; i < 64 * KK; i += 256) {
    int r = i / KK, k = i % KK;
    int n = base + r;
    int val = -1;
    if (n < N && nbr_mask[(size_t)n * KK + k]) val = nbr_idx[(size_t)n * KK + k];
    sm.g.jm[r][k] = val;
  }

  const int r0 = tid >> 3, cc0 = tid & 7;
  const int r1 = r0 + 32,  cc1 = cc0;
  const int sc0 = cc0 ^ (r0 & 7), sc1 = cc1 ^ (r1 & 7);

  __syncthreads();  // jm ready

  uint4 R0 = make_uint4(0u,0u,0u,0u), R1 = R0;
  {
    int j0 = sm.g.jm[r0][0], j1 = sm.g.jm[r1][0];
    uint4 p0 = make_uint4(0u, 0u, 0u, 0u), p1 = p0;
    if (j0 >= 0) p0 = *(const uint4*)(v + (size_t)j0 * PC + cc0 * 8);
    if (j1 >= 0) p1 = *(const uint4*)(v + (size_t)j1 * PC + cc1 * 8);
    int jc = sm.g.jm[r0][1], jd = sm.g.jm[r1][1];
    if (jc >= 0) R0 = *(const uint4*)(v + (size_t)jc * PC + cc0 * 8);
    if (jd >= 0) R1 = *(const uint4*)(v + (size_t)jd * PC + cc1 * 8);
    *(uint4*)(&sm.g.As[0][r0 * 64 + sc0 * 8]) = p0;
    *(uint4*)(&sm.g.As[0][r1 * 64 + sc1 * 8]) = p1;
  }
  __syncthreads();

  f32x4 acc[4][4] = {};
  const ushort* bbase = Bp + (size_t)(lane >> 4) * 2048 + (size_t)((w << 4) + (lane & 15)) * 8;

  int cur = 0, nx = 1;
  for (int kn = 0; kn < KK; ++kn) {
    v8s bf0[4], bf1[4];
    {
      const ushort* bb0 = bbase + (size_t)(8 * kn) * 2048;
      const ushort* bb1 = bb0 + 4 * 2048;
      #pragma unroll
      for (int nt = 0; nt < 4; ++nt) {
        bf0[nt] = *(const v8s*)(bb0 + nt * 512);
        bf1[nt] = *(const v8s*)(bb1 + nt * 512);
      }
    }
    if (kn + 1 < KK) {
      *(uint4*)(&sm.g.As[nx][r0 * 64 + sc0 * 8]) = R0;
      *(uint4*)(&sm.g.As[nx][r1 * 64 + sc1 * 8]) = R1;
    }
    R0 = make_uint4(0u,0u,0u,0u); R1 = R0;
    if (kn + 2 < KK) {
      int j0 = sm.g.jm[r0][kn + 2], j1 = sm.g.jm[r1][kn + 2];
      if (j0 >= 0) R0 = *(const uint4*)(v + (size_t)j0 * PC + cc0 * 8);
      if (j1 >= 0) R1 = *(const uint4*)(v + (size_t)j1 * PC + cc1 * 8);
    }
    #pragma unroll
    for (int s2 = 0; s2 < 2; ++s2) {
      v8s af[4];
      const int cc = s2 * 4 + (lane >> 4);
      #pragma unroll
      for (int mt = 0; mt < 4; ++mt) {
        const int r = mt * 16 + (lane & 15);
        const int sc = cc ^ (r & 7);
        af[mt] = *(const v8s*)(&sm.g.As[cur][r * 64 + sc * 8]);
      }
      #pragma unroll
      for (int mt = 0; mt < 4; ++mt)
        #pragma unroll
        for (int nt = 0; nt < 4; ++nt)
          acc[mt][nt] = __builtin_amdgcn_mfma_f32_16x16x32_bf16(
              af[mt], (s2 ? bf1[nt] : bf0[nt]), acc[mt][nt], 0, 0, 0);
    }
    __syncthreads();
    cur = nx; nx = (nx == 2) ? 0 : nx + 1;
  }

  for (int i2 = tid; i2 < 2048; i2 += 256) {
    int r = i2 >> 5, c = i2 & 31;
    int n = base + r;
    sm.e.xfb[r][c] = (n < N) ? f2b(xf[(size_t)n * INC + c]) : (ushort)0;
  }
  __syncthreads();

  const int ln = lane & 15, grp = lane >> 4;
  const int d = (w << 4) + ln;
  v8s wdf = *(const v8s*)(Wdp + (size_t)d * 32 + grp * 8);
  float bcv[4];
  #pragma unroll
  for (int nt = 0; nt < 4; ++nt) bcv[nt] = bcode[nt * PC + d];
  const float bdv = bd[d];
  #pragma unroll
  for (int mt = 0; mt < 4; ++mt) {
    // residual tile computed inline: only one res f32x4 live at a time
    v8s af = *(const v8s*)(&sm.e.xfb[mt * 16 + ln][grp * 8]);
    f32x4 z = {0.f, 0.f, 0.f, 0.f};
    f32x4 res = __builtin_amdgcn_mfma_f32_16x16x32_bf16(af, wdf, z, 0, 0, 0);
    #pragma unroll
    for (int i = 0; i < 4; ++i) {
      int row = mt * 16 + grp * 4 + i;
      int n = base + row;
      if (n < N) {
        float4 a4 = *(const float4*)(attn + (size_t)n * 4);
        float val = res[i] + bdv;
        val += a4.x * fmaxf(acc[mt][0][i] + bcv[0], 0.f);
        val += a4.y * fmaxf(acc[mt][1][i] + bcv[1], 0.f);
        val += a4.z * fmaxf(acc[mt][2][i] + bcv[2], 0.f);
        val += a4.w * fmaxf(acc[mt][3][i] + bcv[3], 0.f);
        out[(size_t)n * PC + d] = fmaxf(val, 0.f);
      }
    }
  }
}

extern "C" void kernel_launch(void* const* d_in, const int* in_sizes, int n_in,
                              void* d_out, int out_size, void* d_ws, size_t ws_size,
                              hipStream_t stream)
{
  const float* xf     = (const float*)d_in[0];
  const int* nbr_idx  = (const int*)d_in[1];
  const int* nbr_mask = (const int*)d_in[2];
  const int* coords   = (const int*)d_in[3];
  const float* Wt     = (const float*)d_in[4];
  const float* bt     = (const float*)d_in[5];
  const float* Wd     = (const float*)d_in[6];
  const float* bd     = (const float*)d_in[7];
  const float* Wpos   = (const float*)d_in[8];
  const float* bpos   = (const float*)d_in[9];
  const float* Wq     = (const float*)d_in[10];
  const float* bq     = (const float*)d_in[11];
  const float* proj   = (const float*)d_in[12];
  const float* Wv     = (const float*)d_in[13];
  const float* bv     = (const float*)d_in[14];
  const float* Wcode  = (const float*)d_in[15];
  const float* bcode  = (const float*)d_in[16];
  float* out = (float*)d_out;

  int N = in_sizes[0] / INC;

  char* ws = (char*)d_ws;
  size_t off = 0;
  auto alloc = [&](size_t bytes) {
    off = (off + 255) & ~(size_t)255;
    void* p = ws + off;
    off += bytes;
    return p;
  };
  ushort* v_ws  = (ushort*)alloc((size_t)N * PC * 2);
  ushort* zc_ws = (ushort*)alloc((size_t)N * 32 * 2);
  float*  a_ws  = (float*)alloc((size_t)N * 4 * 4);
  ushort* B_ws  = (ushort*)alloc((size_t)54 * 4 * 256 * 8 * 2);
  ushort* D_ws  = (ushort*)alloc((size_t)2048 * 2);
  ushort* T_ws  = (ushort*)alloc((size_t)2048 * 2);
  ushort* V2_ws = (ushort*)alloc((size_t)4096 * 2);
  ushort* Q_ws  = (ushort*)alloc((size_t)2048 * 2);
  (void)ws_size;

  hipLaunchKernelGGL(k_prepBD, dim3(1768), dim3(256), 0, stream,
                     Wcode, Wd, Wt, Wv, Wq, B_ws, D_ws, T_ws, V2_ws, Q_ws);
  hipLaunchKernelGGL(k_prep2, dim3((N + 63) / 64), dim3(256), 0, stream,
                     xf, T_ws, bt, V2_ws, bv, Q_ws, coords, v_ws, zc_ws, N);
  hipLaunchKernelGGL(k_attn2, dim3((N + 7) / 8), dim3(256), 0, stream,
                     nbr_idx, nbr_mask, zc_ws, Wpos, bpos, Wq, bq, proj, a_ws, N);
  hipLaunchKernelGGL(k_code, dim3((N + 63) / 64), dim3(256), 0, stream,
                     v_ws, nbr_idx, nbr_mask, B_ws, a_ws, xf, D_ws, bd, bcode, out, N);
}